// Round 25
// baseline (320.679 us; speedup 1.0000x reference)
//
#include <hip/hip_runtime.h>

// Fused BERT-CRF NER, producer/consumer, 16 waves via __launch_bounds__(1024,4).
//  r22/r24 counters: producers latency-bound (VALUBusy 31%, HBM 10%) at
//  2 waves/SIMD with VGPR=116. The 4-waves/SIMD budget is 128 >= 116 -> fits.
//  r23's collapse (VGPR=64) came from amdgpu_waves_per_eu(4,4); the documented
//  knob is launch_bounds' 2nd arg = min waves/EU: (1024, 4) = 1 block/CU =
//  4 waves/SIMD = 128-reg budget.
//  Waves 1..15: producers, rows r = pw + 15*i (equal shares, ~17 rows).
//  Wave 0: r18 asm Viterbi chain, per-16-row flag gate. Phases 2-5 verbatim.
//  All math bit-identical to r20/r23/r24.
// B=256, T=256, H=768, L=13, START=11.
// Outputs (float32): [0..255] max_p/T; [256..65791] path.

#define NEGV (-10000.0f)

#define DPP_ADD(v, ctrl, rmask)                                               \
  v += __int_as_float(__builtin_amdgcn_update_dpp(                            \
      0, __float_as_int(v), (ctrl), (rmask), 0xF, true));

#define DPP_REDUCE64(v)                                                       \
  DPP_ADD(v, 0x111, 0xF)  /* row_shr:1  */                                    \
  DPP_ADD(v, 0x112, 0xF)  /* row_shr:2  */                                    \
  DPP_ADD(v, 0x114, 0xF)  /* row_shr:4  */                                    \
  DPP_ADD(v, 0x118, 0xF)  /* row_shr:8  */                                    \
  DPP_ADD(v, 0x142, 0xA)  /* row_bcast:15 */                                  \
  DPP_ADD(v, 0x143, 0xC)  /* row_bcast:31 */

// One Viterbi value-step, hand-scheduled (r18, proven).
__device__ __forceinline__ float vstep_asm(float ld, const float* tr, float ft) {
  float out, v0, v1, v2, v3, v4, v5;
  int s0, s1, s2, s3, s4, s5;
  asm("v_readlane_b32 %[s0], %[ld], 0\n\t"
      "v_readlane_b32 %[s1], %[ld], 1\n\t"
      "v_readlane_b32 %[s2], %[ld], 2\n\t"
      "v_readlane_b32 %[s3], %[ld], 3\n\t"
      "v_readlane_b32 %[s4], %[ld], 4\n\t"
      "v_readlane_b32 %[s5], %[ld], 5\n\t"
      "v_add_f32 %[v0], %[s0], %[t0]\n\t"
      "v_add_f32 %[v1], %[s1], %[t1]\n\t"
      "v_add_f32 %[v2], %[s2], %[t2]\n\t"
      "v_readlane_b32 %[s0], %[ld], 6\n\t"
      "v_readlane_b32 %[s1], %[ld], 7\n\t"
      "v_readlane_b32 %[s2], %[ld], 8\n\t"
      "v_add_f32 %[v3], %[s3], %[t3]\n\t"
      "v_add_f32 %[v4], %[s4], %[t4]\n\t"
      "v_add_f32 %[v5], %[s5], %[t5]\n\t"
      "v_max3_f32 %[v0], %[v0], %[v1], %[v2]\n\t"   // m0
      "v_max3_f32 %[v3], %[v3], %[v4], %[v5]\n\t"   // m1
      "v_readlane_b32 %[s3], %[ld], 9\n\t"
      "v_readlane_b32 %[s4], %[ld], 10\n\t"
      "v_readlane_b32 %[s5], %[ld], 11\n\t"
      "v_add_f32 %[v1], %[s0], %[t6]\n\t"
      "v_add_f32 %[v2], %[s1], %[t7]\n\t"
      "v_add_f32 %[v4], %[s2], %[t8]\n\t"
      "v_readlane_b32 %[s0], %[ld], 12\n\t"
      "v_max3_f32 %[v1], %[v1], %[v2], %[v4]\n\t"   // m2
      "v_add_f32 %[v2], %[s3], %[t9]\n\t"
      "v_add_f32 %[v4], %[s4], %[t10]\n\t"
      "v_add_f32 %[v5], %[s5], %[t11]\n\t"
      "v_max3_f32 %[v2], %[v2], %[v4], %[v5]\n\t"   // m3
      "v_add_f32 %[v4], %[s0], %[t12]\n\t"          // c12
      "v_max3_f32 %[v0], %[v0], %[v3], %[v1]\n\t"   // max(m0,m1,m2)
      "v_max3_f32 %[v0], %[v0], %[v2], %[v4]\n\t"   // max(.., m3, c12)
      "v_add_f32 %[o], %[v0], %[ft]"
      : [o] "=&v"(out),
        [s0] "=&s"(s0), [s1] "=&s"(s1), [s2] "=&s"(s2),
        [s3] "=&s"(s3), [s4] "=&s"(s4), [s5] "=&s"(s5),
        [v0] "=&v"(v0), [v1] "=&v"(v1), [v2] "=&v"(v2),
        [v3] "=&v"(v3), [v4] "=&v"(v4), [v5] "=&v"(v5)
      : [ld] "v"(ld), [ft] "v"(ft),
        [t0] "v"(tr[0]), [t1] "v"(tr[1]), [t2] "v"(tr[2]), [t3] "v"(tr[3]),
        [t4] "v"(tr[4]), [t5] "v"(tr[5]), [t6] "v"(tr[6]), [t7] "v"(tr[7]),
        [t8] "v"(tr[8]), [t9] "v"(tr[9]), [t10] "v"(tr[10]),
        [t11] "v"(tr[11]), [t12] "v"(tr[12]));
  return out;
}

__global__ __launch_bounds__(1024, 4)   // 16 waves/block, 1 block/CU -> 128-reg budget
void fused_kernel(
    const float* __restrict__ X,      // [65536, 768]
    const float* __restrict__ W,      // [13, 768]
    const float* __restrict__ bias,   // [13]
    const float* __restrict__ trans,  // [13,13]
    float* __restrict__ out)          // [256 + 65536]
{
  __shared__ float fsT[13 * 260];          // feats transposed [to][t]
  __shared__ float lds_ld[256 * 16];       // ld_t[to]
  __shared__ float trL[176];               // trans (169 used)
  __shared__ unsigned char psi[256 * 16];  // psi[t][to]
  __shared__ unsigned char Mm[256];
  __shared__ unsigned char bnd[16];
  __shared__ unsigned char path[256];
  __shared__ int flags[256];               // per-row ready flags

  const int tid = threadIdx.x;
  const int w = tid >> 6, l = tid & 63;
  const int b = blockIdx.x;

  if (tid < 169) trL[tid] = trans[tid];
  if (tid >= 256 && tid < 512) flags[tid - 256] = 0;
  __syncthreads();

  if (w == 0) {
    // ================== CONSUMER: Viterbi chain (lanes 0-15) ================
    if (l < 16) {
      const int lane = l;
      float tr[13];
      #pragma unroll
      for (int f = 0; f < 13; ++f)
        tr[f] = (lane < 13) ? trans[lane * 13 + f] : -1.0e30f;

      const int toc = (lane < 13) ? lane : 0;
      const float* frow = &fsT[toc * 260];
      volatile int* vf = flags;

      float ld = (lane == 11) ? 0.0f : NEGV;  // START = 11
      lds_ld[lane] = ld;                      // t = 0

      #pragma unroll 1
      for (int g = 0; g < 16; ++g) {
        // wait until all 16 rows of this chunk are produced
        while (!__all(vf[g * 16 + lane] != 0)) {}
        asm volatile("" ::: "memory");

        float4 F[4];
        #pragma unroll
        for (int q = 0; q < 4; ++q)
          F[q] = *reinterpret_cast<const float4*>(frow + g * 16 + 4 * q);

        if (g == 0) {
          #pragma unroll
          for (int k = 1; k < 16; ++k) {
            const float4 fq = F[k >> 2];
            const float ftv = ((k & 3) == 0) ? fq.x : ((k & 3) == 1) ? fq.y
                             : ((k & 3) == 2) ? fq.z : fq.w;
            ld = vstep_asm(ld, tr, ftv);
            lds_ld[k * 16 + lane] = ld;
          }
        } else {
          #pragma unroll
          for (int k = 0; k < 16; ++k) {
            const int t = g * 16 + k;
            const float4 fq = F[k >> 2];
            const float ftv = ((k & 3) == 0) ? fq.x : ((k & 3) == 1) ? fq.y
                             : ((k & 3) == 2) ? fq.z : fq.w;
            ld = vstep_asm(ld, tr, ftv);
            lds_ld[t * 16 + lane] = ld;
          }
        }
      }
    }
  } else {
    // ========= PRODUCERS (waves 1-15): equal-share round-robin rows =========
    const int pw = w - 1;                     // 0..14
    const int imax = (pw == 0) ? 18 : 17;     // rows r = pw + 15i (256 total)

    float wreg[13][12];
    #pragma unroll
    for (int col = 0; col < 13; ++col) {
      #pragma unroll
      for (int j = 0; j < 3; ++j) {
        float4 v = *reinterpret_cast<const float4*>(W + col * 768 + 256 * j + 4 * l);
        wreg[col][4 * j + 0] = v.x; wreg[col][4 * j + 1] = v.y;
        wreg[col][4 * j + 2] = v.z; wreg[col][4 * j + 3] = v.w;
      }
    }
    float bs[13];
    #pragma unroll
    for (int c = 0; c < 13; ++c) bs[c] = bias[c];

    const float* Xb = X + (long)b * 196608 + 4 * l;

    // 4-deep ring prefetch over this wave's rows
    float4 buf[4][3];
    #pragma unroll
    for (int i = 0; i < 4; ++i) {
      const int ri = (i < imax) ? i : imax - 1;
      const float* xr = Xb + (pw + 15 * ri) * 768;
      buf[i][0] = *reinterpret_cast<const float4*>(xr);
      buf[i][1] = *reinterpret_cast<const float4*>(xr + 256);
      buf[i][2] = *reinterpret_cast<const float4*>(xr + 512);
    }

    #pragma unroll 2
    for (int i = 0; i < 18; ++i) {
      if (i < imax) {                       // wave-uniform guard
        const int s = i & 3;
        const int r = pw + 15 * i;
        const float4 b0 = buf[s][0], b1 = buf[s][1], b2 = buf[s][2];

        float acc[13];
        #pragma unroll
        for (int c = 0; c < 13; ++c) acc[c] = 0.0f;
        #pragma unroll
        for (int col = 0; col < 13; ++col) {
          acc[col] = fmaf(b0.x, wreg[col][0],  acc[col]);
          acc[col] = fmaf(b0.y, wreg[col][1],  acc[col]);
          acc[col] = fmaf(b0.z, wreg[col][2],  acc[col]);
          acc[col] = fmaf(b0.w, wreg[col][3],  acc[col]);
          acc[col] = fmaf(b1.x, wreg[col][4],  acc[col]);
          acc[col] = fmaf(b1.y, wreg[col][5],  acc[col]);
          acc[col] = fmaf(b1.z, wreg[col][6],  acc[col]);
          acc[col] = fmaf(b1.w, wreg[col][7],  acc[col]);
          acc[col] = fmaf(b2.x, wreg[col][8],  acc[col]);
          acc[col] = fmaf(b2.y, wreg[col][9],  acc[col]);
          acc[col] = fmaf(b2.z, wreg[col][10], acc[col]);
          acc[col] = fmaf(b2.w, wreg[col][11], acc[col]);
        }

        #pragma unroll
        for (int c = 0; c < 13; ++c) {
          DPP_REDUCE64(acc[c])
        }

        if (l == 63) {
          #pragma unroll
          for (int c = 0; c < 13; ++c)
            fsT[c * 260 + r] = acc[c] + bs[c];
          asm volatile("s_waitcnt lgkmcnt(0)" ::: "memory");
          flags[r] = 1;                     // row complete
        }

        {  // refill slot s (clamped tail: redundant, harmless)
          const int inx = (i + 4 < imax) ? i + 4 : imax - 1;
          const float* xn = Xb + (pw + 15 * inx) * 768;
          buf[s][0] = *reinterpret_cast<const float4*>(xn);
          buf[s][1] = *reinterpret_cast<const float4*>(xn + 256);
          buf[s][2] = *reinterpret_cast<const float4*>(xn + 512);
        }
      }
    }
  }
  __syncthreads();

  // ================== phases 2-5 (r23, 1024-thread indexing) ================
  {
    const int to = tid & 15, dtt = tid >> 4;   // dtt = 0..63
    if (to < 13) {
      float trr[13];
      #pragma unroll
      for (int f = 0; f < 13; ++f) trr[f] = trL[to * 13 + f];
      for (int t = (dtt == 0 ? 64 : dtt); t < 256; t += 64) {
        const float* lp = &lds_ld[(t - 1) * 16];
        float4 l0 = *reinterpret_cast<const float4*>(lp);
        float4 l1 = *reinterpret_cast<const float4*>(lp + 4);
        float4 l2 = *reinterpret_cast<const float4*>(lp + 8);
        float4 l3 = *reinterpret_cast<const float4*>(lp + 12);
        float c[13] = {trr[0] + l0.x,  trr[1] + l0.y,  trr[2] + l0.z,
                       trr[3] + l0.w,  trr[4] + l1.x,  trr[5] + l1.y,
                       trr[6] + l1.z,  trr[7] + l1.w,  trr[8] + l2.x,
                       trr[9] + l2.y,  trr[10] + l2.z, trr[11] + l2.w,
                       trr[12] + l3.x};
        float best = c[0]; int bf = 0;
        #pragma unroll
        for (int f = 1; f < 13; ++f) {
          bool gt = c[f] > best;              // strict >: first index wins
          best = gt ? c[f] : best;
          bf   = gt ? f : bf;
        }
        psi[t * 16 + to] = (unsigned char)bf;
      }
    }
  }
  __syncthreads();

  if (tid < 256) {
    const int sS = tid & 15, g = tid >> 4;
    if (sS < 13) {
      int cur = sS;
      const int tLo = (g == 0) ? 1 : g * 16;
      for (int t = g * 16 + 15; t >= tLo; --t)
        cur = psi[t * 16 + cur];
      Mm[g * 16 + sS] = (unsigned char)cur;
    }
  }
  __syncthreads();

  if (tid == 0) {
    const float* lf = &lds_ld[255 * 16];
    float m = lf[0]; int last = 0;
    #pragma unroll
    for (int i = 1; i < 13; ++i)
      if (lf[i] > m) { m = lf[i]; last = i; }   // strict >: first index
    float ssum = 0.0f;
    #pragma unroll
    for (int i = 0; i < 13; ++i) ssum += expf(lf[i] - m);
    out[b] = 1.0f / (256.0f * ssum);            // max(softmax)/T

    int cur = last;
    bnd[15] = (unsigned char)cur;
    #pragma unroll
    for (int cc = 15; cc >= 1; --cc) {
      cur = Mm[cc * 16 + cur];
      bnd[cc - 1] = (unsigned char)cur;
    }
  }
  __syncthreads();

  if (tid < 16) {
    int cur = bnd[tid];
    const int tHi = tid * 16 + 15;
    path[tHi] = (unsigned char)cur;
    const int tLo = (tid == 0) ? 1 : tid * 16;
    for (int t = tHi; t >= tLo; --t) {
      cur = psi[t * 16 + cur];
      path[t - 1] = (unsigned char)cur;
    }
  }
  __syncthreads();

  if (tid < 256)
    out[256 + (long)b * 256 + tid] = (float)path[tid];
}

// ------------------------------------------------------------------ launch --
extern "C" void kernel_launch(void* const* d_in, const int* in_sizes, int n_in,
                              void* d_out, int out_size, void* d_ws, size_t ws_size,
                              hipStream_t stream) {
  const float* X     = (const float*)d_in[0];
  const float* W     = (const float*)d_in[1];
  const float* bias  = (const float*)d_in[2];
  const float* trans = (const float*)d_in[3];
  float* out = (float*)d_out;

  fused_kernel<<<256, 1024, 0, stream>>>(X, W, bias, trans, out);
}

// Round 27
// 54.533 us; speedup vs baseline: 5.8805x; 5.8805x over previous
//
#include <hip/hip_runtime.h>

// Fused BERT-CRF NER, producer/consumer — r20/r24 base (best 54.7us) with the
// producer row-body re-ordered for ILP (bit-identical per-accumulator op
// sequences; only cross-accumulator interleaving changes):
//  (a) FMA section k-major: 13 independent FMAs between each dependent pair.
//  (b) DPP reduction stage-major: 13 independent DPPs between dependent pairs.
// Compile fix vs r26: dpp_mov is a template<int,int> so update_dpp gets
// constant-integer arguments.
// B=256, T=256, H=768, L=13, START=11.
// Outputs (float32): [0..255] max_p/T; [256..65791] path.

#define NEGV (-10000.0f)

template <int CTRL, int RMASK>
__device__ __forceinline__ float dpp_mov(float v) {
  return __int_as_float(__builtin_amdgcn_update_dpp(
      0, __float_as_int(v), CTRL, RMASK, 0xF, true));
}

// One Viterbi value-step, hand-scheduled (r18, proven).
__device__ __forceinline__ float vstep_asm(float ld, const float* tr, float ft) {
  float out, v0, v1, v2, v3, v4, v5;
  int s0, s1, s2, s3, s4, s5;
  asm("v_readlane_b32 %[s0], %[ld], 0\n\t"
      "v_readlane_b32 %[s1], %[ld], 1\n\t"
      "v_readlane_b32 %[s2], %[ld], 2\n\t"
      "v_readlane_b32 %[s3], %[ld], 3\n\t"
      "v_readlane_b32 %[s4], %[ld], 4\n\t"
      "v_readlane_b32 %[s5], %[ld], 5\n\t"
      "v_add_f32 %[v0], %[s0], %[t0]\n\t"
      "v_add_f32 %[v1], %[s1], %[t1]\n\t"
      "v_add_f32 %[v2], %[s2], %[t2]\n\t"
      "v_readlane_b32 %[s0], %[ld], 6\n\t"
      "v_readlane_b32 %[s1], %[ld], 7\n\t"
      "v_readlane_b32 %[s2], %[ld], 8\n\t"
      "v_add_f32 %[v3], %[s3], %[t3]\n\t"
      "v_add_f32 %[v4], %[s4], %[t4]\n\t"
      "v_add_f32 %[v5], %[s5], %[t5]\n\t"
      "v_max3_f32 %[v0], %[v0], %[v1], %[v2]\n\t"   // m0
      "v_max3_f32 %[v3], %[v3], %[v4], %[v5]\n\t"   // m1
      "v_readlane_b32 %[s3], %[ld], 9\n\t"
      "v_readlane_b32 %[s4], %[ld], 10\n\t"
      "v_readlane_b32 %[s5], %[ld], 11\n\t"
      "v_add_f32 %[v1], %[s0], %[t6]\n\t"
      "v_add_f32 %[v2], %[s1], %[t7]\n\t"
      "v_add_f32 %[v4], %[s2], %[t8]\n\t"
      "v_readlane_b32 %[s0], %[ld], 12\n\t"
      "v_max3_f32 %[v1], %[v1], %[v2], %[v4]\n\t"   // m2
      "v_add_f32 %[v2], %[s3], %[t9]\n\t"
      "v_add_f32 %[v4], %[s4], %[t10]\n\t"
      "v_add_f32 %[v5], %[s5], %[t11]\n\t"
      "v_max3_f32 %[v2], %[v2], %[v4], %[v5]\n\t"   // m3
      "v_add_f32 %[v4], %[s0], %[t12]\n\t"          // c12
      "v_max3_f32 %[v0], %[v0], %[v3], %[v1]\n\t"   // max(m0,m1,m2)
      "v_max3_f32 %[v0], %[v0], %[v2], %[v4]\n\t"   // max(.., m3, c12)
      "v_add_f32 %[o], %[v0], %[ft]"
      : [o] "=&v"(out),
        [s0] "=&s"(s0), [s1] "=&s"(s1), [s2] "=&s"(s2),
        [s3] "=&s"(s3), [s4] "=&s"(s4), [s5] "=&s"(s5),
        [v0] "=&v"(v0), [v1] "=&v"(v1), [v2] "=&v"(v2),
        [v3] "=&v"(v3), [v4] "=&v"(v4), [v5] "=&v"(v5)
      : [ld] "v"(ld), [ft] "v"(ft),
        [t0] "v"(tr[0]), [t1] "v"(tr[1]), [t2] "v"(tr[2]), [t3] "v"(tr[3]),
        [t4] "v"(tr[4]), [t5] "v"(tr[5]), [t6] "v"(tr[6]), [t7] "v"(tr[7]),
        [t8] "v"(tr[8]), [t9] "v"(tr[9]), [t10] "v"(tr[10]),
        [t11] "v"(tr[11]), [t12] "v"(tr[12]));
  return out;
}

__global__ __launch_bounds__(512)
__attribute__((amdgpu_waves_per_eu(2, 2)))
void fused_kernel(
    const float* __restrict__ X,      // [65536, 768]
    const float* __restrict__ W,      // [13, 768]
    const float* __restrict__ bias,   // [13]
    const float* __restrict__ trans,  // [13,13]
    float* __restrict__ out)          // [256 + 65536]
{
  __shared__ float fsT[13 * 260];          // feats transposed [to][t]
  __shared__ float lds_ld[256 * 16];       // ld_t[to]
  __shared__ float trL[176];               // trans (169 used)
  __shared__ unsigned char psi[256 * 16];  // psi[t][to]
  __shared__ unsigned char Mm[256];
  __shared__ unsigned char bnd[16];
  __shared__ unsigned char path[256];
  __shared__ int flags[256];               // per-row ready flags

  const int tid = threadIdx.x;
  const int w = tid >> 6, l = tid & 63;
  const int b = blockIdx.x;

  if (tid < 169) trL[tid] = trans[tid];
  if (tid < 256) flags[tid] = 0;
  __syncthreads();

  if (w == 0) {
    // ================== CONSUMER: Viterbi chain (lanes 0-15) ================
    if (l < 16) {
      const int lane = l;
      float tr[13];
      #pragma unroll
      for (int f = 0; f < 13; ++f)
        tr[f] = (lane < 13) ? trans[lane * 13 + f] : -1.0e30f;

      const int toc = (lane < 13) ? lane : 0;
      const float* frow = &fsT[toc * 260];
      volatile int* vf = flags;

      float ld = (lane == 11) ? 0.0f : NEGV;  // START = 11
      lds_ld[lane] = ld;                      // t = 0

      #pragma unroll 1
      for (int g = 0; g < 16; ++g) {
        while (!__all(vf[g * 16 + lane] != 0)) {}
        asm volatile("" ::: "memory");

        float4 F[4];
        #pragma unroll
        for (int q = 0; q < 4; ++q)
          F[q] = *reinterpret_cast<const float4*>(frow + g * 16 + 4 * q);

        if (g == 0) {
          #pragma unroll
          for (int k = 1; k < 16; ++k) {
            const float4 fq = F[k >> 2];
            const float ftv = ((k & 3) == 0) ? fq.x : ((k & 3) == 1) ? fq.y
                             : ((k & 3) == 2) ? fq.z : fq.w;
            ld = vstep_asm(ld, tr, ftv);
            lds_ld[k * 16 + lane] = ld;
          }
        } else {
          #pragma unroll
          for (int k = 0; k < 16; ++k) {
            const int t = g * 16 + k;
            const float4 fq = F[k >> 2];
            const float ftv = ((k & 3) == 0) ? fq.x : ((k & 3) == 1) ? fq.y
                             : ((k & 3) == 2) ? fq.z : fq.w;
            ld = vstep_asm(ld, tr, ftv);
            lds_ld[t * 16 + lane] = ld;
          }
        }
      }
    }
  } else {
    // ==================== PRODUCERS: feats rows (waves 1-7) =================
    const int pw = w - 1;                    // 0..6
    float wreg[13][12];
    #pragma unroll
    for (int col = 0; col < 13; ++col) {
      #pragma unroll
      for (int j = 0; j < 3; ++j) {
        float4 v = *reinterpret_cast<const float4*>(W + col * 768 + 256 * j + 4 * l);
        wreg[col][4 * j + 0] = v.x; wreg[col][4 * j + 1] = v.y;
        wreg[col][4 * j + 2] = v.z; wreg[col][4 * j + 3] = v.w;
      }
    }
    float bs[13];
    #pragma unroll
    for (int c = 0; c < 13; ++c) bs[c] = bias[c];

    const float* Xb = X + (long)b * 196608 + 4 * l;

    // 4-deep ring: rows pw, pw+7, pw+14, pw+21
    float4 buf[4][3];
    #pragma unroll
    for (int i = 0; i < 4; ++i) {
      const float* xr = Xb + (pw + 7 * i) * 768;
      buf[i][0] = *reinterpret_cast<const float4*>(xr);
      buf[i][1] = *reinterpret_cast<const float4*>(xr + 256);
      buf[i][2] = *reinterpret_cast<const float4*>(xr + 512);
    }

    #define PROW(i, s)                                                        \
    {                                                                         \
      const int r = pw + 7 * (i);                                             \
      const float x[12] = {buf[s][0].x, buf[s][0].y, buf[s][0].z, buf[s][0].w,\
                           buf[s][1].x, buf[s][1].y, buf[s][1].z, buf[s][1].w,\
                           buf[s][2].x, buf[s][2].y, buf[s][2].z, buf[s][2].w};\
      float acc[13];                                                          \
      _Pragma("unroll")                                                       \
      for (int c = 0; c < 13; ++c) acc[c] = 0.0f;                             \
      /* K-MAJOR: 13 independent FMAs between dependent pairs; each acc      */\
      /* still accumulates k=0..11 ascending -> bit-identical values.        */\
      _Pragma("unroll")                                                       \
      for (int k = 0; k < 12; ++k)                                            \
        _Pragma("unroll")                                                     \
        for (int c = 0; c < 13; ++c)                                          \
          acc[c] = fmaf(x[k], wreg[c][k], acc[c]);                            \
      /* STAGE-MAJOR DPP reduce: per-acc sequence unchanged -> bit-identical */\
      _Pragma("unroll")                                                       \
      for (int c = 0; c < 13; ++c) acc[c] += dpp_mov<0x111, 0xF>(acc[c]);     \
      _Pragma("unroll")                                                       \
      for (int c = 0; c < 13; ++c) acc[c] += dpp_mov<0x112, 0xF>(acc[c]);     \
      _Pragma("unroll")                                                       \
      for (int c = 0; c < 13; ++c) acc[c] += dpp_mov<0x114, 0xF>(acc[c]);     \
      _Pragma("unroll")                                                       \
      for (int c = 0; c < 13; ++c) acc[c] += dpp_mov<0x118, 0xF>(acc[c]);     \
      _Pragma("unroll")                                                       \
      for (int c = 0; c < 13; ++c) acc[c] += dpp_mov<0x142, 0xA>(acc[c]);     \
      _Pragma("unroll")                                                       \
      for (int c = 0; c < 13; ++c) acc[c] += dpp_mov<0x143, 0xC>(acc[c]);     \
      if (l == 63) {                                                          \
        _Pragma("unroll")                                                     \
        for (int c = 0; c < 13; ++c)                                          \
          fsT[c * 260 + r] = acc[c] + bs[c];                                  \
        asm volatile("s_waitcnt lgkmcnt(0)" ::: "memory");                    \
        flags[r] = 1;                                                         \
      }                                                                       \
    }

    #pragma unroll 4
    for (int i = 0; i < 36; ++i) {
      const int s = i & 3;
      PROW(i, s)
      {  // refill slot s with row i+4 (clamped; tail loads unused/duplicate)
        const int rn = pw + 7 * (i + 4);
        const int rc = (rn < 256) ? rn : 255;
        const float* xn = Xb + rc * 768;
        buf[s][0] = *reinterpret_cast<const float4*>(xn);
        buf[s][1] = *reinterpret_cast<const float4*>(xn + 256);
        buf[s][2] = *reinterpret_cast<const float4*>(xn + 512);
      }
    }
    if (pw < 4) {          // peeled i=36 (waves 1-4 own rows 252..255)
      PROW(36, 0)
    }
    #undef PROW
  }
  __syncthreads();

  // ================== phases 2-5 (verbatim r20, 512 threads) ================
  {
    const int to = tid & 15, dtt = tid >> 4;   // dtt = 0..31
    if (to < 13) {
      float trr[13];
      #pragma unroll
      for (int f = 0; f < 13; ++f) trr[f] = trL[to * 13 + f];
      for (int t = (dtt == 0 ? 32 : dtt); t < 256; t += 32) {
        const float* lp = &lds_ld[(t - 1) * 16];
        float4 l0 = *reinterpret_cast<const float4*>(lp);
        float4 l1 = *reinterpret_cast<const float4*>(lp + 4);
        float4 l2 = *reinterpret_cast<const float4*>(lp + 8);
        float4 l3 = *reinterpret_cast<const float4*>(lp + 12);
        float c[13] = {trr[0] + l0.x,  trr[1] + l0.y,  trr[2] + l0.z,
                       trr[3] + l0.w,  trr[4] + l1.x,  trr[5] + l1.y,
                       trr[6] + l1.z,  trr[7] + l1.w,  trr[8] + l2.x,
                       trr[9] + l2.y,  trr[10] + l2.z, trr[11] + l2.w,
                       trr[12] + l3.x};
        float best = c[0]; int bf = 0;
        #pragma unroll
        for (int f = 1; f < 13; ++f) {
          bool gt = c[f] > best;              // strict >: first index wins
          best = gt ? c[f] : best;
          bf   = gt ? f : bf;
        }
        psi[t * 16 + to] = (unsigned char)bf;
      }
    }
  }
  __syncthreads();

  if (tid < 256) {
    const int sS = tid & 15, g = tid >> 4;
    if (sS < 13) {
      int cur = sS;
      const int tLo = (g == 0) ? 1 : g * 16;
      for (int t = g * 16 + 15; t >= tLo; --t)
        cur = psi[t * 16 + cur];
      Mm[g * 16 + sS] = (unsigned char)cur;
    }
  }
  __syncthreads();

  if (tid == 0) {
    const float* lf = &lds_ld[255 * 16];
    float m = lf[0]; int last = 0;
    #pragma unroll
    for (int i = 1; i < 13; ++i)
      if (lf[i] > m) { m = lf[i]; last = i; }   // strict >: first index
    float ssum = 0.0f;
    #pragma unroll
    for (int i = 0; i < 13; ++i) ssum += expf(lf[i] - m);
    out[b] = 1.0f / (256.0f * ssum);            // max(softmax)/T

    int cur = last;
    bnd[15] = (unsigned char)cur;
    #pragma unroll
    for (int cc = 15; cc >= 1; --cc) {
      cur = Mm[cc * 16 + cur];
      bnd[cc - 1] = (unsigned char)cur;
    }
  }
  __syncthreads();

  if (tid < 16) {
    int cur = bnd[tid];
    const int tHi = tid * 16 + 15;
    path[tHi] = (unsigned char)cur;
    const int tLo = (tid == 0) ? 1 : tid * 16;
    for (int t = tHi; t >= tLo; --t) {
      cur = psi[t * 16 + cur];
      path[t - 1] = (unsigned char)cur;
    }
  }
  __syncthreads();

  if (tid < 256)
    out[256 + (long)b * 256 + tid] = (float)path[tid];
}

// ------------------------------------------------------------------ launch --
extern "C" void kernel_launch(void* const* d_in, const int* in_sizes, int n_in,
                              void* d_out, int out_size, void* d_ws, size_t ws_size,
                              hipStream_t stream) {
  const float* X     = (const float*)d_in[0];
  const float* W     = (const float*)d_in[1];
  const float* bias  = (const float*)d_in[2];
  const float* trans = (const float*)d_in[3];
  float* out = (float*)d_out;

  fused_kernel<<<256, 512, 0, stream>>>(X, W, bias, trans, out);
}